// Round 4
// baseline (147.097 us; speedup 1.0000x reference)
//
#include <hip/hip_runtime.h>
#include <math.h>

#define ACT_SHIFT -4.5951198501345889f
#define SB 96                       // samples per MLP chunk
#define NSLOTMAX (4096*446)
#define MLP_BLOCKS 1024

typedef _Float16 f16;
typedef f16 f16x8 __attribute__((ext_vector_type(8)));
typedef f16 f16x2 __attribute__((ext_vector_type(2)));
typedef float f32x4 __attribute__((ext_vector_type(4)));

// ---- workspace layout (bytes) ----
#define OFF_CNT  0
#define OFF_RAYI 256                        // int4 * 4096
#define OFF_RAYF (OFF_RAYI + 4096*16)       // float2 * 4096 {tmin, nrm}
#define OFF_EMBW (OFF_RAYF + 4096*8)        // float * 4096*64
#define OFF_WTS  (OFF_EMBW + 4096*64*4)     // f16 * 47104
#define OFF_SLOT (OFF_WTS + 94208)          // int * NSLOTMAX
#define OFF_WS4H (OFF_SLOT + NSLOTMAX*4)    // ushort4 (f16 alpha,r,g,b) * NSLOTMAX

// weight slab offsets (f16 elements), layout Wt[dout][din_padded]
#define W_MW1 0       /* 128 x 32  */
#define W_MW2 4096    /* 128 x 128 */
#define W_MW3 20480   /* 32  x 128 */
#define W_FV  24576   /* 64  x 32  */
#define W_P1  26624   /* 64  x 64  */
#define W_P2  30720   /* 64  x 64  */
#define W_P3  34816   /* 16  x 64  */
#define W_D1  35840   /* 64  x 32  */
#define W_D2  37888   /* 64  x 64  */
#define W_D3  41984   /* 64  x 64  */
#define W_D4  46080   /* 16  x 64  */
#define W_TOT 47104

static __device__ __forceinline__ unsigned short f2h(float x) {
  f16 h = (f16)x; return *(unsigned short*)&h;
}
static __device__ __forceinline__ float h2f(unsigned short u) {
  return (float)(*(f16*)&u);
}

// LDS-only barrier: drain DS ops, raw s_barrier — does NOT drain vmcnt, so
// register-prefetch global loads stay in flight across layers.
static __device__ __forceinline__ void bar_lds() {
  asm volatile("s_waitcnt lgkmcnt(0)" ::: "memory");
  __builtin_amdgcn_s_barrier();
}

// identical math in setup & mlp kernels (validity must agree bit-exactly)
static __device__ __forceinline__ void sample_point(
    float ox, float oy, float oz, float dx, float dy, float dz,
    float tmin, float nrm, int s, float& px, float& py, float& pz) {
  float ix = tmin + (0.0078125f * (float)s) / nrm;
  px = ox + dx * ix; py = oy + dy * ix; pz = oz + dz * ix;
}
static __device__ __forceinline__ int in_box(float px, float py, float pz) {
  return !(px < -1.f || px > 1.f || py < -1.f || py > 1.f ||
           pz < -1.f || pz > 1.f);
}

static __device__ __forceinline__ bool ray_setup(
    const float* rays_o, const float* rays_d, int r,
    float& ox, float& oy, float& oz, float& dx, float& dy, float& dz,
    float& tmin, float& nrm) {
  ox = rays_o[r*3+0]; oy = rays_o[r*3+1]; oz = rays_o[r*3+2];
  dx = rays_d[r*3+0]; dy = rays_d[r*3+1]; dz = rays_d[r*3+2];
  const float vx = (dx == 0.0f) ? 1e-6f : dx;
  const float vy = (dy == 0.0f) ? 1e-6f : dy;
  const float vz = (dz == 0.0f) ? 1e-6f : dz;
  const float rax = ( 1.0f - ox) / vx, rbx = (-1.0f - ox) / vx;
  const float ray_ = ( 1.0f - oy) / vy, rby = (-1.0f - oy) / vy;
  const float raz = ( 1.0f - oz) / vz, rbz = (-1.0f - oz) / vz;
  tmin = fmaxf(fmaxf(fminf(rax,rbx), fminf(ray_,rby)), fminf(raz,rbz));
  tmin = fminf(fmaxf(tmin, 0.2f), 3.0f);
  float tmax = fminf(fminf(fmaxf(rax,rbx), fmaxf(ray_,rby)), fmaxf(raz,rbz));
  tmax = fminf(fmaxf(tmax, 0.2f), 3.0f);
  nrm = sqrtf(dx*dx + dy*dy + dz*dz);
  return tmax <= tmin;  // miss
}

// ============ kernel 1: analytic per-ray valid sample range ============
// Computes a SUPERSET (±1 sample margin) of the valid range; k_mlp re-checks
// in_box per sample exactly, and invalid samples contribute alpha=0 → safe.
extern "C" __global__ void __launch_bounds__(256)
k_setup(const float* __restrict__ rays_o, const float* __restrict__ rays_d,
        int* __restrict__ cnt, int4* __restrict__ rayi,
        float2* __restrict__ rayf) {
  int r = blockIdx.x * 256 + threadIdx.x;
  if (r >= 4096) return;
  float ox,oy,oz,dx,dy,dz,tmin,nrm;
  bool miss = ray_setup(rays_o, rays_d, r, ox,oy,oz,dx,dy,dz, tmin, nrm);
  rayf[r] = make_float2(tmin, nrm);
  if (miss) { rayi[r] = make_int4(0,0,0,0); return; }

  float lo = -1e30f, hi = 1e30f;
  float o3[3] = {ox,oy,oz}, d3[3] = {dx,dy,dz};
#pragma unroll
  for (int c = 0; c < 3; ++c) {
    float o = o3[c], d = d3[c];
    if (d == 0.0f) {
      if (o < -1.f || o > 1.f) { lo = 1e30f; hi = -1e30f; }
    } else {
      float t1 = (-1.f - o) / d, t2 = (1.f - o) / d;
      lo = fmaxf(lo, fminf(t1, t2));
      hi = fminf(hi, fmaxf(t1, t2));
    }
  }
  float k = 0.0078125f / nrm;
  float sf = (lo - tmin) / k - 1.0f;          // margin
  float lf = (hi - tmin) / k + 1.0f;
  int first = (int)ceilf (fmaxf(0.f,  fminf(445.f, sf)));
  int last  = (int)floorf(fmaxf(-1.f, fminf(445.f, lf)));
  int n_s = (lf >= sf && last >= first) ? (last - first + 1) : 0;
  int base = 0;
  if (n_s > 0) base = atomicAdd(cnt, n_s);
  rayi[r] = make_int4(base, first, n_s, 0);
}

// ============ kernel 1b: parallel slot_map fill ============
extern "C" __global__ void __launch_bounds__(64)
k_fill(const int4* __restrict__ rayi, int* __restrict__ slot_map) {
  int r = blockIdx.x;
  int4 ri = rayi[r];
  for (int i = threadIdx.x; i < ri.z; i += 64)
    slot_map[ri.x + i] = (r << 9) | (ri.y + i);
}

// ============ kernel 2: per-ray dir-embed folded into dW1 -> embW ============
extern "C" __global__ void __launch_bounds__(256)
k_embw(const float* __restrict__ viewdirs, const float* __restrict__ dW1,
       const float* __restrict__ db1, float* __restrict__ embW) {
  int idx = blockIdx.x * 256 + threadIdx.x;
  if (idx >= 4096*64) return;
  int ray = idx >> 6, o = idx & 63;
  float v0 = viewdirs[ray*3+0], v1 = viewdirs[ray*3+1], v2 = viewdirs[ray*3+2];
  float acc = db1[o];
  acc = fmaf(v0, dW1[15*64+o], acc);
  acc = fmaf(v1, dW1[16*64+o], acc);
  acc = fmaf(v2, dW1[17*64+o], acc);
#pragma unroll
  for (int fr = 0; fr < 6; ++fr) {
    float f = (float)(1 << fr);
    int rb = 18 + fr*6;
    acc = fmaf(sinf(v0*f), dW1[(rb+0)*64+o], acc);
    acc = fmaf(sinf(v1*f), dW1[(rb+1)*64+o], acc);
    acc = fmaf(sinf(v2*f), dW1[(rb+2)*64+o], acc);
    acc = fmaf(cosf(v0*f), dW1[(rb+3)*64+o], acc);
    acc = fmaf(cosf(v1*f), dW1[(rb+4)*64+o], acc);
    acc = fmaf(cosf(v2*f), dW1[(rb+5)*64+o], acc);
  }
  embW[idx] = acc;
}

// ============ kernel 3: transpose/pad all weights to f16 Wt[dout][din] ========
extern "C" __global__ void __launch_bounds__(256)
k_pack(const float* __restrict__ mW1, const float* __restrict__ mW2,
       const float* __restrict__ mW3, const float* __restrict__ fv,
       const float* __restrict__ pW1, const float* __restrict__ pW2,
       const float* __restrict__ pW3, const float* __restrict__ dW1,
       const float* __restrict__ dW2, const float* __restrict__ dW3,
       const float* __restrict__ dW4, f16* __restrict__ wts) {
  int i = blockIdx.x * 256 + threadIdx.x;
  if (i >= W_TOT) return;
  float v = 0.f; int l, o, k;
  if (i < W_MW2)        { l=i-W_MW1; o=l>>5; k=l&31;  if (k<4)  v = mW1[k*128+o]; }
  else if (i < W_MW3)   { l=i-W_MW2; o=l>>7; k=l&127; v = mW2[k*128+o]; }
  else if (i < W_FV)    { l=i-W_MW3; o=l>>7; k=l&127; v = mW3[k*32+o]; }
  else if (i < W_P1)    { l=i-W_FV;  o=l>>5; k=l&31;  v = fv[k*64+o]; }
  else if (i < W_P2)    { l=i-W_P1;  o=l>>6; k=l&63;  v = pW1[k*64+o]; }
  else if (i < W_P3)    { l=i-W_P2;  o=l>>6; k=l&63;  v = pW2[k*64+o]; }
  else if (i < W_D1)    { l=i-W_P3;  o=l>>6; k=l&63;  v = pW3[k*16+o]; }
  else if (i < W_D2)    { l=i-W_D1;  o=l>>5; k=l&31;  if (k<15) v = dW1[k*64+o]; }
  else if (i < W_D3)    { l=i-W_D2;  o=l>>6; k=l&63;  v = dW2[k*64+o]; }
  else if (i < W_D4)    { l=i-W_D3;  o=l>>6; k=l&63;  v = dW3[k*64+o]; }
  else                  { l=i-W_D4;  o=l>>6; k=l&63;  if (o<3)  v = dW4[k*3+o]; }
  wts[i] = (f16)v;
}

// ---- generic MFMA layer over SB=96 samples, NW waves split output tiles ----
// BMODE: 0 none, 1 colwise f32 bias, 2 per-ray embW bias, 3 pos-head, 4 rgb-head
template<int KP, int NP, bool RELU, int BMODE, int NW>
__device__ __forceinline__ void layer_mm(
    const f16* __restrict__ Wt, const float* __restrict__ bias,
    const float* __restrict__ embW, const int* sinfo,
    const f16* inb, f16* outb, int wave, int lane,
    int blockbase, unsigned short* ws4h) {
  constexpr int MB = SB/16, NB = NP/16, NT = MB*NB, TPW = (NT+NW-1)/NW, KS = KP/32;
  const int c = lane & 15, g = lane >> 4;
  f16x8 Bf[KS];
  int prev_nb = -1;
  for (int ti = 0; ti < TPW; ++ti) {
    int t = wave * TPW + ti;
    if (t >= NT) break;
    int nb = t / MB, mb = t % MB;
    if (nb != prev_nb) {
      prev_nb = nb;
      const f16* wp = Wt + (size_t)(nb*16 + c) * KP + g*8;
#pragma unroll
      for (int ks = 0; ks < KS; ++ks)
        Bf[ks] = *(const f16x8*)(wp + ks*32);
    }
    f32x4 acc = {0.f, 0.f, 0.f, 0.f};
#pragma unroll
    for (int ks = 0; ks < KS; ++ks) {
      int row = mb*16 + c;
      int off = (row*256 + (ks*32 + g*8)*2) ^ ((row & 7) << 4);
      f16x8 Af = *(const f16x8*)((const char*)inb + off);
      acc = __builtin_amdgcn_mfma_f32_16x16x32_f16(Af, Bf[ks], acc, 0, 0, 0);
    }
    int cc = nb*16 + c;
    float bv = 0.f;
    if (BMODE == 1 || BMODE == 3 || BMODE == 4) bv = bias[cc];
#pragma unroll
    for (int r = 0; r < 4; ++r) {
      int row = mb*16 + g*4 + r;
      float bb = bv;
      if (BMODE == 2) {
        int pk = sinfo[row];
        int ry = (pk < 0) ? 0 : (pk >> 1);
        bb = embW[ry*64 + cc];
      }
      float v = acc[r] + bb;
      if (BMODE <= 2) {
        if (RELU) v = fmaxf(v, 0.f);
        int off = (row*256 + cc*2) ^ ((row & 7) << 4);
        *(f16*)((char*)outb + off) = (f16)v;
      } else if (BMODE == 3) {          // pos head: alpha (cc==0) + rgb_latent
        int pk = sinfo[row];
        if (cc == 0) {
          if (pk >= 0) {
            float a = 0.f;
            if (pk & 1) {
              float x = v + ACT_SHIFT;
              float sp = fmaxf(x, 0.f) + log1pf(expf(-fabsf(x)));
              a = 1.f - expf(-sp);
            }
            ws4h[(size_t)(blockbase + row)*4 + 0] = f2h(a);
          }
        } else {
          int off = (row*256 + (cc-1)*2) ^ ((row & 7) << 4);
          *(f16*)((char*)outb + off) = (f16)v;
        }
      } else {                          // BMODE 4: rgb head
        int pk = sinfo[row];
        if (pk >= 0 && cc < 3) {
          float rv = (pk & 1) ? (1.f / (1.f + expf(-v))) : 0.f;
          ws4h[(size_t)(blockbase + row)*4 + 1 + cc] = f2h(rv);
        }
      }
    }
  }
}

// ---- prefetch registers: one interp channel per thread (tid<384) ----
struct Pf {
  float v[8];
  float fx, fy, fz;
  int pk;
};

static __device__ __forceinline__ void pf_issue(
    int slot, int total, int c,
    const int* __restrict__ slot_map, const float2* __restrict__ rayf,
    const float* __restrict__ rays_o, const float* __restrict__ rays_d,
    const float* __restrict__ grid, Pf& P) {
  if (slot >= total) {
    P.pk = -2; P.fx = P.fy = P.fz = 0.f;
#pragma unroll
    for (int i = 0; i < 8; ++i) P.v[i] = 0.f;
    return;
  }
  int mi = slot_map[slot];
  int ray = mi >> 9, s = mi & 511;
  float2 tf = rayf[ray];
  float ox = rays_o[ray*3+0], oy = rays_o[ray*3+1], oz = rays_o[ray*3+2];
  float dx = rays_d[ray*3+0], dy = rays_d[ray*3+1], dz = rays_d[ray*3+2];
  float px, py, pz;
  sample_point(ox,oy,oz,dx,dy,dz, tf.x, tf.y, s, px,py,pz);
  P.pk = ray*2 + in_box(px,py,pz);
  float ixf = fminf(fmaxf((px + 1.f) * 0.5f * 255.f, 0.f), 255.f);
  float iyf = fminf(fmaxf((py + 1.f) * 0.5f * 255.f, 0.f), 255.f);
  float izf = fminf(fmaxf((pz + 1.f) * 0.5f * 255.f, 0.f), 255.f);
  int x0 = min((int)ixf, 254), y0 = min((int)iyf, 254), z0 = min((int)izf, 254);
  P.fx = ixf - (float)x0; P.fy = iyf - (float)y0; P.fz = izf - (float)z0;
  const float* gc = grid + (size_t)c * 16777216u;
  int bx0 = x0 << 16, bx1 = bx0 + 65536;
  int by0 = y0 << 8,  by1 = by0 + 256;
  P.v[0] = gc[bx0+by0+z0]; P.v[1] = gc[bx0+by0+z0+1];
  P.v[2] = gc[bx0+by1+z0]; P.v[3] = gc[bx0+by1+z0+1];
  P.v[4] = gc[bx1+by0+z0]; P.v[5] = gc[bx1+by0+z0+1];
  P.v[6] = gc[bx1+by1+z0]; P.v[7] = gc[bx1+by1+z0+1];
}

// ============ kernel 4: persistent packed-sample MFMA MLP pipeline ============
extern "C" __global__ void __launch_bounds__(512)
k_mlp(const float* __restrict__ rays_o, const float* __restrict__ rays_d,
      const float* __restrict__ grid, const int* __restrict__ slot_map,
      const float2* __restrict__ rayf, const float* __restrict__ embW,
      const f16* __restrict__ wts, const int* __restrict__ cnt,
      const float* __restrict__ mb1, const float* __restrict__ mb2,
      const float* __restrict__ mb3, const float* __restrict__ pb1,
      const float* __restrict__ pb2, const float* __restrict__ pb3,
      const float* __restrict__ db2, const float* __restrict__ db3,
      const float* __restrict__ db4, unsigned short* __restrict__ ws4h) {
  const int total = *cnt;
  const int nch = (total + SB - 1) / SB;
  const int tid = threadIdx.x;
  const int wave = tid >> 6, lane = tid & 63;
  const int sl = tid >> 2, ch = tid & 3;        // interp mapping (tid<384)

  __shared__ __align__(16) f16 X[SB*128];
  __shared__ __align__(16) f16 Y[SB*128];
  __shared__ int sinfo[SB];

  Pf P;
  // prologue prefetch for this block's first chunk
  if (tid < SB*4)
    pf_issue(blockIdx.x * SB + sl, total, ch, slot_map, rayf, rays_o, rays_d,
             grid, P);

  for (int chunk = blockIdx.x; chunk < nch; chunk += gridDim.x) {
    const int blockbase = chunk * SB;

    // ---- consume prefetch: trilinear from regs -> X, sinfo ----
    if (tid < SB*4) {
      float c00 = P.v[0]*(1.f-P.fz) + P.v[1]*P.fz;
      float c01 = P.v[2]*(1.f-P.fz) + P.v[3]*P.fz;
      float c10 = P.v[4]*(1.f-P.fz) + P.v[5]*P.fz;
      float c11 = P.v[6]*(1.f-P.fz) + P.v[7]*P.fz;
      float c0v = c00*(1.f-P.fy) + c01*P.fy;
      float c1v = c10*(1.f-P.fy) + c11*P.fy;
      float mv  = c0v*(1.f-P.fx) + c1v*P.fx;
      if (ch == 0) sinfo[sl] = P.pk;
      int off = (sl*256 + ch*2) ^ ((sl & 7) << 4);
      *(f16*)((char*)X + off) = (f16)mv;
    }
    // zero pad dims 4..31 of X (first layer reads KP=32)
    for (int idx = tid; idx < SB*14; idx += 512) {
      int row = idx / 14, dim = 4 + (idx % 14)*2;
      int off = (row*256 + dim*2) ^ ((row & 7) << 4);
      f16x2 z = {(f16)0.f, (f16)0.f};
      *(f16x2*)((char*)X + off) = z;
    }
    // ---- issue prefetch for the next chunk (stays in flight across layers) --
    if (tid < SB*4)
      pf_issue((chunk + gridDim.x) * SB + sl, total, ch, slot_map, rayf,
               rays_o, rays_d, grid, P);
    bar_lds();

    layer_mm<32,128,true,1,8>(wts+W_MW1, mb1, nullptr, sinfo, X, Y, wave, lane, blockbase, ws4h);
    bar_lds();
    layer_mm<128,128,true,1,8>(wts+W_MW2, mb2, nullptr, sinfo, Y, X, wave, lane, blockbase, ws4h);
    bar_lds();
    layer_mm<128,32,false,1,8>(wts+W_MW3, mb3, nullptr, sinfo, X, Y, wave, lane, blockbase, ws4h);
    bar_lds();

    // softmax over 32 logits, thread per sample
    if (tid < SB) {
      int row = tid;
      float v[32];
#pragma unroll
      for (int p = 0; p < 16; ++p) {
        int off = (row*256 + p*4) ^ ((row & 7) << 4);
        f16x2 two = *(const f16x2*)((const char*)Y + off);
        v[2*p] = (float)two[0]; v[2*p+1] = (float)two[1];
      }
      float m = -1e30f;
#pragma unroll
      for (int i = 0; i < 32; ++i) m = fmaxf(m, v[i]);
      float sum = 0.f;
#pragma unroll
      for (int i = 0; i < 32; ++i) { v[i] = expf(v[i] - m); sum += v[i]; }
      float inv = 1.f / sum;
#pragma unroll
      for (int p = 0; p < 16; ++p) {
        int off = (row*256 + p*4) ^ ((row & 7) << 4);
        f16x2 two = {(f16)(v[2*p]*inv), (f16)(v[2*p+1]*inv)};
        *(f16x2*)((char*)Y + off) = two;
      }
    }
    bar_lds();

    layer_mm<32,64,false,0,8>(wts+W_FV, nullptr, nullptr, sinfo, Y, X, wave, lane, blockbase, ws4h);
    bar_lds();
    layer_mm<64,64,true,1,8>(wts+W_P1, pb1, nullptr, sinfo, X, Y, wave, lane, blockbase, ws4h);
    bar_lds();
    layer_mm<64,64,true,1,8>(wts+W_P2, pb2, nullptr, sinfo, Y, X, wave, lane, blockbase, ws4h);
    bar_lds();
    layer_mm<64,16,false,3,8>(wts+W_P3, pb3, nullptr, sinfo, X, Y, wave, lane, blockbase, ws4h);
    bar_lds();
    layer_mm<32,64,true,2,8>(wts+W_D1, nullptr, embW, sinfo, Y, X, wave, lane, blockbase, ws4h);
    bar_lds();
    layer_mm<64,64,true,1,8>(wts+W_D2, db2, nullptr, sinfo, X, Y, wave, lane, blockbase, ws4h);
    bar_lds();
    layer_mm<64,64,true,1,8>(wts+W_D3, db3, nullptr, sinfo, Y, X, wave, lane, blockbase, ws4h);
    bar_lds();
    layer_mm<64,16,false,4,8>(wts+W_D4, db4, nullptr, sinfo, X, Y, wave, lane, blockbase, ws4h);
    bar_lds();   // protect X/sinfo overwrite by next chunk's consume
  }
}

// ============ kernel 5: per-ray transmittance scan over packed slots ==========
extern "C" __global__ void __launch_bounds__(256)
k_scan(const ushort4* __restrict__ ws4h, const int4* __restrict__ rayi,
       float* __restrict__ out) {
  const int wid = (blockIdx.x * 256 + threadIdx.x) >> 6;
  const int ln  = threadIdx.x & 63;
  if (wid >= 4096) return;
  int4 ri = rayi[wid];
  int base = ri.x, n_s = ri.z;

  float T = 1.0f, ar = 0.f, ag = 0.f, ab = 0.f;
  int nc = (n_s + 63) >> 6;
  for (int cck = 0; cck < nc; ++cck) {
    int j = cck*64 + ln;
    float a = 0.f, rr = 0.f, gg = 0.f, bb = 0.f;
    if (j < n_s) {
      ushort4 u = ws4h[(size_t)base + j];
      a = h2f(u.x); rr = h2f(u.y); gg = h2f(u.z); bb = h2f(u.w);
    }
    float p = fmaxf(1.0f - a, 1e-10f);
#pragma unroll
    for (int off = 1; off < 64; off <<= 1) {
      float o = __shfl_up(p, off);
      if (ln >= off) p *= o;
    }
    float pe = __shfl_up(p, 1);
    if (ln == 0) pe = 1.0f;
    float wgt = a * T * pe;
    ar = fmaf(wgt, rr, ar);
    ag = fmaf(wgt, gg, ag);
    ab = fmaf(wgt, bb, ab);
    T *= __shfl(p, 63);
  }
#pragma unroll
  for (int off = 32; off; off >>= 1) {
    ar += __shfl_down(ar, off);
    ag += __shfl_down(ag, off);
    ab += __shfl_down(ab, off);
  }
  if (ln == 0) {
    out[wid*3+0] = ar + T;
    out[wid*3+1] = ag + T;
    out[wid*3+2] = ab + T;
  }
}

extern "C" void kernel_launch(void* const* d_in, const int* in_sizes, int n_in,
                              void* d_out, int out_size, void* d_ws, size_t ws_size,
                              hipStream_t stream) {
  const float* rays_o   = (const float*)d_in[0];
  const float* rays_d   = (const float*)d_in[1];
  const float* viewdirs = (const float*)d_in[2];
  const float* grid     = (const float*)d_in[3];
  const float* fv       = (const float*)d_in[4];
  const float* mW1 = (const float*)d_in[5];  const float* mb1 = (const float*)d_in[6];
  const float* mW2 = (const float*)d_in[7];  const float* mb2 = (const float*)d_in[8];
  const float* mW3 = (const float*)d_in[9];  const float* mb3 = (const float*)d_in[10];
  const float* pW1 = (const float*)d_in[11]; const float* pb1 = (const float*)d_in[12];
  const float* pW2 = (const float*)d_in[13]; const float* pb2 = (const float*)d_in[14];
  const float* pW3 = (const float*)d_in[15]; const float* pb3 = (const float*)d_in[16];
  const float* dW1 = (const float*)d_in[17]; const float* db1 = (const float*)d_in[18];
  const float* dW2 = (const float*)d_in[19]; const float* db2 = (const float*)d_in[20];
  const float* dW3 = (const float*)d_in[21]; const float* db3 = (const float*)d_in[22];
  const float* dW4 = (const float*)d_in[23]; const float* db4 = (const float*)d_in[24];
  float* out = (float*)d_out;

  char* ws = (char*)d_ws;
  int*     cnt      = (int*)(ws + OFF_CNT);
  int4*    rayi     = (int4*)(ws + OFF_RAYI);
  float2*  rayf     = (float2*)(ws + OFF_RAYF);
  float*   embW     = (float*)(ws + OFF_EMBW);
  f16*     wts      = (f16*)(ws + OFF_WTS);
  int*     slot_map = (int*)(ws + OFF_SLOT);
  unsigned short* ws4h = (unsigned short*)(ws + OFF_WS4H);

  hipMemsetAsync(cnt, 0, 4, stream);
  k_setup<<<16, 256, 0, stream>>>(rays_o, rays_d, cnt, rayi, rayf);
  k_fill<<<4096, 64, 0, stream>>>(rayi, slot_map);
  k_embw<<<1024, 256, 0, stream>>>(viewdirs, dW1, db1, embW);
  k_pack<<<(W_TOT+255)/256, 256, 0, stream>>>(mW1, mW2, mW3, fv, pW1, pW2, pW3,
                                              dW1, dW2, dW3, dW4, wts);
  k_mlp<<<MLP_BLOCKS, 512, 0, stream>>>(rays_o, rays_d, grid, slot_map, rayf,
                                        embW, wts, cnt, mb1, mb2, mb3,
                                        pb1, pb2, pb3, db2, db3, db4, ws4h);
  k_scan<<<1024, 256, 0, stream>>>((const ushort4*)ws4h, rayi, out);
}

// Round 5
// 105.403 us; speedup vs baseline: 1.3956x; 1.3956x over previous
//
#include <hip/hip_runtime.h>
#include <math.h>

#define ACT_SHIFT -4.5951198501345889f
#define SB 96                       // samples per MLP chunk
#define NSLOTMAX (4096*446)
#define MLP_BLOCKS 1024

typedef _Float16 f16;
typedef f16 f16x8 __attribute__((ext_vector_type(8)));
typedef f16 f16x4 __attribute__((ext_vector_type(4)));
typedef f16 f16x2 __attribute__((ext_vector_type(2)));
typedef float f32x4 __attribute__((ext_vector_type(4)));

// ---- workspace layout (bytes) ----
#define OFF_CNT  0
#define OFF_RAYI 256                        // int4 * 4096
#define OFF_RAYF (OFF_RAYI + 4096*16)       // float2 * 4096 {tmin, nrm}
#define OFF_EMBW (OFF_RAYF + 4096*8)        // float * 4096*64
#define OFF_WTS  (OFF_EMBW + 4096*64*4)     // f16 * 47104
#define OFF_SLOT (OFF_WTS + 94208)          // int * NSLOTMAX
#define OFF_WS4H (OFF_SLOT + NSLOTMAX*4)    // ushort4 (f16 alpha,r,g,b) * NSLOTMAX

// weight slab offsets (f16 elements), layout Wt[dout][din_padded]
#define W_MW1 0       /* 128 x 32  */
#define W_MW2 4096    /* 128 x 128 */
#define W_MW3 20480   /* 32  x 128 */
#define W_FV  24576   /* 64  x 32  */
#define W_P1  26624   /* 64  x 64  */
#define W_P2  30720   /* 64  x 64  */
#define W_P3  34816   /* 16  x 64  */
#define W_D1  35840   /* 64  x 32  */
#define W_D2  37888   /* 64  x 64  */
#define W_D3  41984   /* 64  x 64  */
#define W_D4  46080   /* 16  x 64  */
#define W_TOT 47104

static __device__ __forceinline__ unsigned short f2h(float x) {
  f16 h = (f16)x; return *(unsigned short*)&h;
}
static __device__ __forceinline__ float h2f(unsigned short u) {
  return (float)(*(f16*)&u);
}

// LDS-only barrier: drain DS ops, raw s_barrier — does NOT drain vmcnt.
static __device__ __forceinline__ void bar_lds() {
  asm volatile("s_waitcnt lgkmcnt(0)" ::: "memory");
  __builtin_amdgcn_s_barrier();
}

static __device__ __forceinline__ void sample_point(
    float ox, float oy, float oz, float dx, float dy, float dz,
    float tmin, float nrm, int s, float& px, float& py, float& pz) {
  float ix = tmin + (0.0078125f * (float)s) / nrm;
  px = ox + dx * ix; py = oy + dy * ix; pz = oz + dz * ix;
}
static __device__ __forceinline__ int in_box(float px, float py, float pz) {
  return !(px < -1.f || px > 1.f || py < -1.f || py > 1.f ||
           pz < -1.f || pz > 1.f);
}

static __device__ __forceinline__ bool ray_setup(
    const float* rays_o, const float* rays_d, int r,
    float& ox, float& oy, float& oz, float& dx, float& dy, float& dz,
    float& tmin, float& nrm) {
  ox = rays_o[r*3+0]; oy = rays_o[r*3+1]; oz = rays_o[r*3+2];
  dx = rays_d[r*3+0]; dy = rays_d[r*3+1]; dz = rays_d[r*3+2];
  const float vx = (dx == 0.0f) ? 1e-6f : dx;
  const float vy = (dy == 0.0f) ? 1e-6f : dy;
  const float vz = (dz == 0.0f) ? 1e-6f : dz;
  const float rax = ( 1.0f - ox) / vx, rbx = (-1.0f - ox) / vx;
  const float ray_ = ( 1.0f - oy) / vy, rby = (-1.0f - oy) / vy;
  const float raz = ( 1.0f - oz) / vz, rbz = (-1.0f - oz) / vz;
  tmin = fmaxf(fmaxf(fminf(rax,rbx), fminf(ray_,rby)), fminf(raz,rbz));
  tmin = fminf(fmaxf(tmin, 0.2f), 3.0f);
  float tmax = fminf(fminf(fmaxf(rax,rbx), fmaxf(ray_,rby)), fmaxf(raz,rbz));
  tmax = fminf(fmaxf(tmax, 0.2f), 3.0f);
  nrm = sqrtf(dx*dx + dy*dy + dz*dz);
  return tmax <= tmin;  // miss
}

// ============ kernel 1: analytic per-ray valid sample range (superset) ========
extern "C" __global__ void __launch_bounds__(256)
k_setup(const float* __restrict__ rays_o, const float* __restrict__ rays_d,
        int* __restrict__ cnt, int4* __restrict__ rayi,
        float2* __restrict__ rayf) {
  int r = blockIdx.x * 256 + threadIdx.x;
  if (r >= 4096) return;
  float ox,oy,oz,dx,dy,dz,tmin,nrm;
  bool miss = ray_setup(rays_o, rays_d, r, ox,oy,oz,dx,dy,dz, tmin, nrm);
  rayf[r] = make_float2(tmin, nrm);
  if (miss) { rayi[r] = make_int4(0,0,0,0); return; }

  float lo = -1e30f, hi = 1e30f;
  float o3[3] = {ox,oy,oz}, d3[3] = {dx,dy,dz};
#pragma unroll
  for (int c = 0; c < 3; ++c) {
    float o = o3[c], d = d3[c];
    if (d == 0.0f) {
      if (o < -1.f || o > 1.f) { lo = 1e30f; hi = -1e30f; }
    } else {
      float t1 = (-1.f - o) / d, t2 = (1.f - o) / d;
      lo = fmaxf(lo, fminf(t1, t2));
      hi = fminf(hi, fmaxf(t1, t2));
    }
  }
  float k = 0.0078125f / nrm;
  float sf = (lo - tmin) / k - 1.0f;
  float lf = (hi - tmin) / k + 1.0f;
  int first = (int)ceilf (fmaxf(0.f,  fminf(445.f, sf)));
  int last  = (int)floorf(fmaxf(-1.f, fminf(445.f, lf)));
  int n_s = (lf >= sf && last >= first) ? (last - first + 1) : 0;
  int base = 0;
  if (n_s > 0) base = atomicAdd(cnt, n_s);
  rayi[r] = make_int4(base, first, n_s, 0);
}

// ============ kernel 1b: parallel slot_map fill ============
extern "C" __global__ void __launch_bounds__(64)
k_fill(const int4* __restrict__ rayi, int* __restrict__ slot_map) {
  int r = blockIdx.x;
  int4 ri = rayi[r];
  for (int i = threadIdx.x; i < ri.z; i += 64)
    slot_map[ri.x + i] = (r << 9) | (ri.y + i);
}

// ============ kernel 2: per-ray dir-embed folded into dW1 -> embW ============
extern "C" __global__ void __launch_bounds__(256)
k_embw(const float* __restrict__ viewdirs, const float* __restrict__ dW1,
       const float* __restrict__ db1, float* __restrict__ embW) {
  int idx = blockIdx.x * 256 + threadIdx.x;
  if (idx >= 4096*64) return;
  int ray = idx >> 6, o = idx & 63;
  float v0 = viewdirs[ray*3+0], v1 = viewdirs[ray*3+1], v2 = viewdirs[ray*3+2];
  float acc = db1[o];
  acc = fmaf(v0, dW1[15*64+o], acc);
  acc = fmaf(v1, dW1[16*64+o], acc);
  acc = fmaf(v2, dW1[17*64+o], acc);
#pragma unroll
  for (int fr = 0; fr < 6; ++fr) {
    float f = (float)(1 << fr);
    int rb = 18 + fr*6;
    acc = fmaf(sinf(v0*f), dW1[(rb+0)*64+o], acc);
    acc = fmaf(sinf(v1*f), dW1[(rb+1)*64+o], acc);
    acc = fmaf(sinf(v2*f), dW1[(rb+2)*64+o], acc);
    acc = fmaf(cosf(v0*f), dW1[(rb+3)*64+o], acc);
    acc = fmaf(cosf(v1*f), dW1[(rb+4)*64+o], acc);
    acc = fmaf(cosf(v2*f), dW1[(rb+5)*64+o], acc);
  }
  embW[idx] = acc;
}

// ============ kernel 3: transpose/pad weights to f16 Wt[dout][din] ============
// NOTE: W_D1 k=0 is a zero column (latent now stored at dims 1..15, dim0=0).
extern "C" __global__ void __launch_bounds__(256)
k_pack(const float* __restrict__ mW1, const float* __restrict__ mW2,
       const float* __restrict__ mW3, const float* __restrict__ fv,
       const float* __restrict__ pW1, const float* __restrict__ pW2,
       const float* __restrict__ pW3, const float* __restrict__ dW1,
       const float* __restrict__ dW2, const float* __restrict__ dW3,
       const float* __restrict__ dW4, f16* __restrict__ wts) {
  int i = blockIdx.x * 256 + threadIdx.x;
  if (i >= W_TOT) return;
  float v = 0.f; int l, o, k;
  if (i < W_MW2)        { l=i-W_MW1; o=l>>5; k=l&31;  if (k<4)  v = mW1[k*128+o]; }
  else if (i < W_MW3)   { l=i-W_MW2; o=l>>7; k=l&127; v = mW2[k*128+o]; }
  else if (i < W_FV)    { l=i-W_MW3; o=l>>7; k=l&127; v = mW3[k*32+o]; }
  else if (i < W_P1)    { l=i-W_FV;  o=l>>5; k=l&31;  v = fv[k*64+o]; }
  else if (i < W_P2)    { l=i-W_P1;  o=l>>6; k=l&63;  v = pW1[k*64+o]; }
  else if (i < W_P3)    { l=i-W_P2;  o=l>>6; k=l&63;  v = pW2[k*64+o]; }
  else if (i < W_D1)    { l=i-W_P3;  o=l>>6; k=l&63;  v = pW3[k*16+o]; }
  else if (i < W_D2)    { l=i-W_D1;  o=l>>5; k=l&31;  if (k>=1 && k<16) v = dW1[(k-1)*64+o]; }
  else if (i < W_D3)    { l=i-W_D2;  o=l>>6; k=l&63;  v = dW2[k*64+o]; }
  else if (i < W_D4)    { l=i-W_D3;  o=l>>6; k=l&63;  v = dW3[k*64+o]; }
  else                  { l=i-W_D4;  o=l>>6; k=l&63;  if (o<3)  v = dW4[k*3+o]; }
  wts[i] = (f16)v;
}

// ---- MFMA layer, SWAPPED operands: D[dout][sample] = W · X^T ----
// C layout: col(lane&15)=sample, rows((lane>>4)*4+r)=4 consecutive douts
// => packed f16x4 ds_write_b64 per tile per lane.
// BMODE: 0 none, 1 colwise bias, 2 per-ray embW bias, 3 pos-head, 4 rgb-head
template<int KP, int NP, bool RELU, int BMODE, int NW>
__device__ __forceinline__ void layer_mm(
    const f16* __restrict__ Wt, const float* __restrict__ bias,
    const float* __restrict__ embW, const int* sinfo,
    const f16* inb, f16* outb, int wave, int lane,
    int blockbase, unsigned short* ws4h, float& alpha_reg, int& pk_reg) {
  constexpr int ST = SB/16, MT = NP/16, NT = MT*ST, TPW = (NT+NW-1)/NW, KS = KP/32;
  const int c = lane & 15, g = lane >> 4;
  f16x8 Af[KS];
  f32x4 b4 = {0.f,0.f,0.f,0.f};
  int prev_dt = -1;
#pragma unroll
  for (int ti = 0; ti < TPW; ++ti) {
    int t = wave * TPW + ti;
    if (t >= NT) break;
    int dt = t / ST, st = t % ST;
    if (dt != prev_dt) {
      prev_dt = dt;
      const f16* wp = Wt + (size_t)(dt*16 + c) * KP + g*8;
#pragma unroll
      for (int ks = 0; ks < KS; ++ks)
        Af[ks] = *(const f16x8*)(wp + ks*32);
      if (BMODE == 1 || BMODE == 3 || BMODE == 4)
        b4 = *(const f32x4*)(bias + dt*16 + g*4);
    }
    const int row = st*16 + c;                 // sample row in LDS
    f32x4 acc = {0.f,0.f,0.f,0.f};
#pragma unroll
    for (int ks = 0; ks < KS; ++ks) {
      int off = (row*256 + (ks*32 + g*8)*2) ^ ((row & 7) << 4);
      f16x8 Bf = *(const f16x8*)((const char*)inb + off);
      acc = __builtin_amdgcn_mfma_f32_16x16x32_f16(Af[ks], Bf, acc, 0, 0, 0);
    }
    if (BMODE == 2) {
      int pk = sinfo[row];
      int ry = (pk < 0) ? 0 : (pk >> 1);
      b4 = *(const f32x4*)(embW + ry*64 + dt*16 + g*4);
    }
    float v0 = acc[0]+b4[0], v1 = acc[1]+b4[1];
    float v2 = acc[2]+b4[2], v3 = acc[3]+b4[3];
    if (BMODE <= 2) {
      if (RELU) {
        v0 = fmaxf(v0,0.f); v1 = fmaxf(v1,0.f);
        v2 = fmaxf(v2,0.f); v3 = fmaxf(v3,0.f);
      }
      f16x4 o = {(f16)v0,(f16)v1,(f16)v2,(f16)v3};
      int off = (row*256 + (dt*16 + g*4)*2) ^ ((row & 7) << 4);
      *(f16x4*)((char*)outb + off) = o;
    } else if (BMODE == 3) {     // pos head (NP=16, dt=0): alpha + latent
      pk_reg = sinfo[row];
      if (g == 0) {
        float a = 0.f;
        if (pk_reg >= 0 && (pk_reg & 1)) {
          float x = v0 + ACT_SHIFT;
          float sp = fmaxf(x, 0.f) + log1pf(expf(-fabsf(x)));
          a = 1.f - expf(-sp);
        }
        alpha_reg = a;
        v0 = 0.f;                // dim0 of latent buffer = 0 (weight col 0 is 0)
      }
      f16x4 o = {(f16)v0,(f16)v1,(f16)v2,(f16)v3};
      int off = (row*256 + (g*4)*2) ^ ((row & 7) << 4);
      *(f16x4*)((char*)outb + off) = o;
    } else {                     // BMODE 4: rgb head (NP=16, dt=0)
      if (g == 0 && pk_reg >= 0) {
        bool val = (pk_reg & 1) != 0;
        ushort4 u;
        u.x = f2h(alpha_reg);
        u.y = f2h(val ? (1.f/(1.f+expf(-v0))) : 0.f);
        u.z = f2h(val ? (1.f/(1.f+expf(-v1))) : 0.f);
        u.w = f2h(val ? (1.f/(1.f+expf(-v2))) : 0.f);
        *(ushort4*)(ws4h + (size_t)(blockbase + row)*4) = u;
      }
    }
  }
}

// ---- prefetch registers: one interp channel per thread (tid<384) ----
struct Pf {
  float v[8];
  float fx, fy, fz;
  int pk;
};

static __device__ __forceinline__ void pf_issue(
    int slot, int total, int c,
    const int* __restrict__ slot_map, const float2* __restrict__ rayf,
    const float* __restrict__ rays_o, const float* __restrict__ rays_d,
    const float* __restrict__ grid, Pf& P) {
  if (slot >= total) {
    P.pk = -2; P.fx = P.fy = P.fz = 0.f;
#pragma unroll
    for (int i = 0; i < 8; ++i) P.v[i] = 0.f;
    return;
  }
  int mi = slot_map[slot];
  int ray = mi >> 9, s = mi & 511;
  float2 tf = rayf[ray];
  float ox = rays_o[ray*3+0], oy = rays_o[ray*3+1], oz = rays_o[ray*3+2];
  float dx = rays_d[ray*3+0], dy = rays_d[ray*3+1], dz = rays_d[ray*3+2];
  float px, py, pz;
  sample_point(ox,oy,oz,dx,dy,dz, tf.x, tf.y, s, px,py,pz);
  P.pk = ray*2 + in_box(px,py,pz);
  float ixf = fminf(fmaxf((px + 1.f) * 0.5f * 255.f, 0.f), 255.f);
  float iyf = fminf(fmaxf((py + 1.f) * 0.5f * 255.f, 0.f), 255.f);
  float izf = fminf(fmaxf((pz + 1.f) * 0.5f * 255.f, 0.f), 255.f);
  int x0 = min((int)ixf, 254), y0 = min((int)iyf, 254), z0 = min((int)izf, 254);
  P.fx = ixf - (float)x0; P.fy = iyf - (float)y0; P.fz = izf - (float)z0;
  const float* gc = grid + (size_t)c * 16777216u;
  int bx0 = x0 << 16, bx1 = bx0 + 65536;
  int by0 = y0 << 8,  by1 = by0 + 256;
  P.v[0] = gc[bx0+by0+z0]; P.v[1] = gc[bx0+by0+z0+1];
  P.v[2] = gc[bx0+by1+z0]; P.v[3] = gc[bx0+by1+z0+1];
  P.v[4] = gc[bx1+by0+z0]; P.v[5] = gc[bx1+by0+z0+1];
  P.v[6] = gc[bx1+by1+z0]; P.v[7] = gc[bx1+by1+z0+1];
}

// ============ kernel 4: persistent packed-sample MFMA MLP pipeline ============
extern "C" __global__ void __launch_bounds__(512)
k_mlp(const float* __restrict__ rays_o, const float* __restrict__ rays_d,
      const float* __restrict__ grid, const int* __restrict__ slot_map,
      const float2* __restrict__ rayf, const float* __restrict__ embW,
      const f16* __restrict__ wts, const int* __restrict__ cnt,
      const float* __restrict__ mb1, const float* __restrict__ mb2,
      const float* __restrict__ mb3, const float* __restrict__ pb1,
      const float* __restrict__ pb2, const float* __restrict__ pb3,
      const float* __restrict__ db2, const float* __restrict__ db3,
      const float* __restrict__ db4, unsigned short* __restrict__ ws4h) {
  const int total = *cnt;
  const int nch = (total + SB - 1) / SB;
  const int tid = threadIdx.x;
  const int wave = tid >> 6, lane = tid & 63;
  const int sl = tid >> 2, ch = tid & 3;        // interp mapping (tid<384)

  __shared__ __align__(16) f16 X[SB*128];
  __shared__ __align__(16) f16 Y[SB*128];
  __shared__ int sinfo[SB];

  Pf P;
  if (tid < SB*4)
    pf_issue(blockIdx.x * SB + sl, total, ch, slot_map, rayf, rays_o, rays_d,
             grid, P);

  for (int chunk = blockIdx.x; chunk < nch; chunk += gridDim.x) {
    const int blockbase = chunk * SB;
    float alpha_reg = 0.f; int pk_reg = -2;

    // ---- consume prefetch: trilinear from regs -> X, sinfo ----
    if (tid < SB*4) {
      float c00 = P.v[0]*(1.f-P.fz) + P.v[1]*P.fz;
      float c01 = P.v[2]*(1.f-P.fz) + P.v[3]*P.fz;
      float c10 = P.v[4]*(1.f-P.fz) + P.v[5]*P.fz;
      float c11 = P.v[6]*(1.f-P.fz) + P.v[7]*P.fz;
      float c0v = c00*(1.f-P.fy) + c01*P.fy;
      float c1v = c10*(1.f-P.fy) + c11*P.fy;
      float mv  = c0v*(1.f-P.fx) + c1v*P.fx;
      if (ch == 0) sinfo[sl] = P.pk;
      int off = (sl*256 + ch*2) ^ ((sl & 7) << 4);
      *(f16*)((char*)X + off) = (f16)mv;
    }
    for (int idx = tid; idx < SB*14; idx += 512) {
      int row = idx / 14, dim = 4 + (idx % 14)*2;
      int off = (row*256 + dim*2) ^ ((row & 7) << 4);
      f16x2 z = {(f16)0.f, (f16)0.f};
      *(f16x2*)((char*)X + off) = z;
    }
    if (tid < SB*4)
      pf_issue((chunk + gridDim.x) * SB + sl, total, ch, slot_map, rayf,
               rays_o, rays_d, grid, P);
    bar_lds();

    layer_mm<32,128,true,1,8>(wts+W_MW1, mb1, nullptr, sinfo, X, Y, wave, lane, blockbase, ws4h, alpha_reg, pk_reg);
    bar_lds();
    layer_mm<128,128,true,1,8>(wts+W_MW2, mb2, nullptr, sinfo, Y, X, wave, lane, blockbase, ws4h, alpha_reg, pk_reg);
    bar_lds();
    layer_mm<128,32,false,1,8>(wts+W_MW3, mb3, nullptr, sinfo, X, Y, wave, lane, blockbase, ws4h, alpha_reg, pk_reg);
    bar_lds();

    // softmax over 32 logits, thread per sample
    if (tid < SB) {
      int row = tid;
      float v[32];
#pragma unroll
      for (int p = 0; p < 16; ++p) {
        int off = (row*256 + p*4) ^ ((row & 7) << 4);
        f16x2 two = *(const f16x2*)((const char*)Y + off);
        v[2*p] = (float)two[0]; v[2*p+1] = (float)two[1];
      }
      float m = -1e30f;
#pragma unroll
      for (int i = 0; i < 32; ++i) m = fmaxf(m, v[i]);
      float sum = 0.f;
#pragma unroll
      for (int i = 0; i < 32; ++i) { v[i] = expf(v[i] - m); sum += v[i]; }
      float inv = 1.f / sum;
#pragma unroll
      for (int p = 0; p < 16; ++p) {
        int off = (row*256 + p*4) ^ ((row & 7) << 4);
        f16x2 two = {(f16)(v[2*p]*inv), (f16)(v[2*p+1]*inv)};
        *(f16x2*)((char*)Y + off) = two;
      }
    }
    bar_lds();

    layer_mm<32,64,false,0,8>(wts+W_FV, nullptr, nullptr, sinfo, Y, X, wave, lane, blockbase, ws4h, alpha_reg, pk_reg);
    bar_lds();
    layer_mm<64,64,true,1,8>(wts+W_P1, pb1, nullptr, sinfo, X, Y, wave, lane, blockbase, ws4h, alpha_reg, pk_reg);
    bar_lds();
    layer_mm<64,64,true,1,8>(wts+W_P2, pb2, nullptr, sinfo, Y, X, wave, lane, blockbase, ws4h, alpha_reg, pk_reg);
    bar_lds();
    layer_mm<64,16,false,3,8>(wts+W_P3, pb3, nullptr, sinfo, X, Y, wave, lane, blockbase, ws4h, alpha_reg, pk_reg);
    bar_lds();
    layer_mm<32,64,true,2,8>(wts+W_D1, nullptr, embW, sinfo, Y, X, wave, lane, blockbase, ws4h, alpha_reg, pk_reg);
    bar_lds();
    layer_mm<64,64,true,1,8>(wts+W_D2, db2, nullptr, sinfo, X, Y, wave, lane, blockbase, ws4h, alpha_reg, pk_reg);
    bar_lds();
    layer_mm<64,64,true,1,8>(wts+W_D3, db3, nullptr, sinfo, Y, X, wave, lane, blockbase, ws4h, alpha_reg, pk_reg);
    bar_lds();
    layer_mm<64,16,false,4,8>(wts+W_D4, db4, nullptr, sinfo, X, Y, wave, lane, blockbase, ws4h, alpha_reg, pk_reg);
    bar_lds();   // protect X/sinfo overwrite by next chunk's consume
  }
}

// ============ kernel 5: per-ray transmittance scan over packed slots ==========
extern "C" __global__ void __launch_bounds__(256)
k_scan(const ushort4* __restrict__ ws4h, const int4* __restrict__ rayi,
       float* __restrict__ out) {
  const int wid = (blockIdx.x * 256 + threadIdx.x) >> 6;
  const int ln  = threadIdx.x & 63;
  if (wid >= 4096) return;
  int4 ri = rayi[wid];
  int base = ri.x, n_s = ri.z;

  float T = 1.0f, ar = 0.f, ag = 0.f, ab = 0.f;
  int nc = (n_s + 63) >> 6;
  for (int cck = 0; cck < nc; ++cck) {
    int j = cck*64 + ln;
    float a = 0.f, rr = 0.f, gg = 0.f, bb = 0.f;
    if (j < n_s) {
      ushort4 u = ws4h[(size_t)base + j];
      a = h2f(u.x); rr = h2f(u.y); gg = h2f(u.z); bb = h2f(u.w);
    }
    float p = fmaxf(1.0f - a, 1e-10f);
#pragma unroll
    for (int off = 1; off < 64; off <<= 1) {
      float o = __shfl_up(p, off);
      if (ln >= off) p *= o;
    }
    float pe = __shfl_up(p, 1);
    if (ln == 0) pe = 1.0f;
    float wgt = a * T * pe;
    ar = fmaf(wgt, rr, ar);
    ag = fmaf(wgt, gg, ag);
    ab = fmaf(wgt, bb, ab);
    T *= __shfl(p, 63);
  }
#pragma unroll
  for (int off = 32; off; off >>= 1) {
    ar += __shfl_down(ar, off);
    ag += __shfl_down(ag, off);
    ab += __shfl_down(ab, off);
  }
  if (ln == 0) {
    out[wid*3+0] = ar + T;
    out[wid*3+1] = ag + T;
    out[wid*3+2] = ab + T;
  }
}

extern "C" void kernel_launch(void* const* d_in, const int* in_sizes, int n_in,
                              void* d_out, int out_size, void* d_ws, size_t ws_size,
                              hipStream_t stream) {
  const float* rays_o   = (const float*)d_in[0];
  const float* rays_d   = (const float*)d_in[1];
  const float* viewdirs = (const float*)d_in[2];
  const float* grid     = (const float*)d_in[3];
  const float* fv       = (const float*)d_in[4];
  const float* mW1 = (const float*)d_in[5];  const float* mb1 = (const float*)d_in[6];
  const float* mW2 = (const float*)d_in[7];  const float* mb2 = (const float*)d_in[8];
  const float* mW3 = (const float*)d_in[9];  const float* mb3 = (const float*)d_in[10];
  const float* pW1 = (const float*)d_in[11]; const float* pb1 = (const float*)d_in[12];
  const float* pW2 = (const float*)d_in[13]; const float* pb2 = (const float*)d_in[14];
  const float* pW3 = (const float*)d_in[15]; const float* pb3 = (const float*)d_in[16];
  const float* dW1 = (const float*)d_in[17]; const float* db1 = (const float*)d_in[18];
  const float* dW2 = (const float*)d_in[19]; const float* db2 = (const float*)d_in[20];
  const float* dW3 = (const float*)d_in[21]; const float* db3 = (const float*)d_in[22];
  const float* dW4 = (const float*)d_in[23]; const float* db4 = (const float*)d_in[24];
  float* out = (float*)d_out;

  char* ws = (char*)d_ws;
  int*     cnt      = (int*)(ws + OFF_CNT);
  int4*    rayi     = (int4*)(ws + OFF_RAYI);
  float2*  rayf     = (float2*)(ws + OFF_RAYF);
  float*   embW     = (float*)(ws + OFF_EMBW);
  f16*     wts      = (f16*)(ws + OFF_WTS);
  int*     slot_map = (int*)(ws + OFF_SLOT);
  unsigned short* ws4h = (unsigned short*)(ws + OFF_WS4H);

  hipMemsetAsync(cnt, 0, 4, stream);
  k_setup<<<16, 256, 0, stream>>>(rays_o, rays_d, cnt, rayi, rayf);
  k_fill<<<4096, 64, 0, stream>>>(rayi, slot_map);
  k_embw<<<1024, 256, 0, stream>>>(viewdirs, dW1, db1, embW);
  k_pack<<<(W_TOT+255)/256, 256, 0, stream>>>(mW1, mW2, mW3, fv, pW1, pW2, pW3,
                                              dW1, dW2, dW3, dW4, wts);
  k_mlp<<<MLP_BLOCKS, 512, 0, stream>>>(rays_o, rays_d, grid, slot_map, rayf,
                                        embW, wts, cnt, mb1, mb2, mb3,
                                        pb1, pb2, pb3, db2, db3, db4, ws4h);
  k_scan<<<1024, 256, 0, stream>>>((const ushort4*)ws4h, rayi, out);
}

// Round 7
// 103.246 us; speedup vs baseline: 1.4247x; 1.0209x over previous
//
#include <hip/hip_runtime.h>
#include <math.h>

#define ACT_SHIFT -4.5951198501345889f
#define SB 128                      // samples per MLP chunk
#define NSLOTMAX (4096*446)

typedef _Float16 f16;
typedef f16 f16x8 __attribute__((ext_vector_type(8)));
typedef f16 f16x4 __attribute__((ext_vector_type(4)));
typedef float f32x4 __attribute__((ext_vector_type(4)));
typedef float f32x16 __attribute__((ext_vector_type(16)));

// ---- workspace layout (bytes) ----
#define OFF_CNT  0                          // int cnt, int qhead
#define OFF_RAYI 256                        // int4 * 4096
#define OFF_RAYF (OFF_RAYI + 4096*16)       // float2 * 4096 {tmin, nrm}
#define OFF_EMBW (OFF_RAYF + 4096*8)        // float * 4096*64
#define OFF_WTS  (OFF_EMBW + 4096*64*4)     // f16 * 46080
#define OFF_BIAS (OFF_WTS + 92160)          // float * 1408 (11 layers x 128)
#define OFF_SLOT (OFF_BIAS + 8192)          // int * NSLOTMAX
#define OFF_WS4H (OFF_SLOT + NSLOTMAX*4)    // ushort4 * NSLOTMAX

// weight slab offsets (f16 elements), Wt[dout][KP] row-major
#define W_MW1 0        /* 128 x 16  */
#define W_MW2 2048     /* 128 x 128 */
#define W_MW3 18432    /* 32  x 128 */
#define W_FV  22528    /* 64  x 32  */
#define W_P1  24576    /* 64  x 64  */
#define W_P2  28672    /* 64  x 64  */
#define W_P3  32768    /* 32  x 64  (douts 16-31 zero-pad) */
#define W_D1  34816    /* 64  x 16  (k=0 zero col) */
#define W_D2  35840    /* 64  x 64  */
#define W_D3  39936    /* 64  x 64  */
#define W_D4  44032    /* 32  x 64  (douts 3-31 zero-pad) */
#define W_TOT 46080

static __device__ __forceinline__ unsigned short f2h(float x) {
  f16 h = (f16)x; return *(unsigned short*)&h;
}
static __device__ __forceinline__ float h2f(unsigned short u) {
  return (float)(*(f16*)&u);
}

// LDS-only barrier: does NOT drain vmcnt (prefetch stays in flight).
static __device__ __forceinline__ void bar_lds() {
  asm volatile("s_waitcnt lgkmcnt(0)" ::: "memory");
  __builtin_amdgcn_s_barrier();
}

static __device__ __forceinline__ void sample_point(
    float ox, float oy, float oz, float dx, float dy, float dz,
    float tmin, float nrm, int s, float& px, float& py, float& pz) {
  float ix = tmin + (0.0078125f * (float)s) / nrm;
  px = ox + dx * ix; py = oy + dy * ix; pz = oz + dz * ix;
}
static __device__ __forceinline__ int in_box(float px, float py, float pz) {
  return !(px < -1.f || px > 1.f || py < -1.f || py > 1.f ||
           pz < -1.f || pz > 1.f);
}

static __device__ __forceinline__ bool ray_setup(
    const float* rays_o, const float* rays_d, int r,
    float& ox, float& oy, float& oz, float& dx, float& dy, float& dz,
    float& tmin, float& nrm) {
  ox = rays_o[r*3+0]; oy = rays_o[r*3+1]; oz = rays_o[r*3+2];
  dx = rays_d[r*3+0]; dy = rays_d[r*3+1]; dz = rays_d[r*3+2];
  const float vx = (dx == 0.0f) ? 1e-6f : dx;
  const float vy = (dy == 0.0f) ? 1e-6f : dy;
  const float vz = (dz == 0.0f) ? 1e-6f : dz;
  const float rax = ( 1.0f - ox) / vx, rbx = (-1.0f - ox) / vx;
  const float ray_ = ( 1.0f - oy) / vy, rby = (-1.0f - oy) / vy;
  const float raz = ( 1.0f - oz) / vz, rbz = (-1.0f - oz) / vz;
  tmin = fmaxf(fmaxf(fminf(rax,rbx), fminf(ray_,rby)), fminf(raz,rbz));
  tmin = fminf(fmaxf(tmin, 0.2f), 3.0f);
  float tmax = fminf(fminf(fmaxf(rax,rbx), fmaxf(ray_,rby)), fmaxf(raz,rbz));
  tmax = fminf(fmaxf(tmax, 0.2f), 3.0f);
  nrm = sqrtf(dx*dx + dy*dy + dz*dz);
  return tmax <= tmin;  // miss
}

// ============ kernel 1: analytic per-ray valid sample range (superset) ========
extern "C" __global__ void __launch_bounds__(256)
k_setup(const float* __restrict__ rays_o, const float* __restrict__ rays_d,
        int* __restrict__ cnt, int4* __restrict__ rayi,
        float2* __restrict__ rayf) {
  int r = blockIdx.x * 256 + threadIdx.x;
  if (r >= 4096) return;
  float ox,oy,oz,dx,dy,dz,tmin,nrm;
  bool miss = ray_setup(rays_o, rays_d, r, ox,oy,oz,dx,dy,dz, tmin, nrm);
  rayf[r] = make_float2(tmin, nrm);
  if (miss) { rayi[r] = make_int4(0,0,0,0); return; }

  float lo = -1e30f, hi = 1e30f;
  float o3[3] = {ox,oy,oz}, d3[3] = {dx,dy,dz};
#pragma unroll
  for (int c = 0; c < 3; ++c) {
    float o = o3[c], d = d3[c];
    if (d == 0.0f) {
      if (o < -1.f || o > 1.f) { lo = 1e30f; hi = -1e30f; }
    } else {
      float t1 = (-1.f - o) / d, t2 = (1.f - o) / d;
      lo = fmaxf(lo, fminf(t1, t2));
      hi = fminf(hi, fmaxf(t1, t2));
    }
  }
  float k = 0.0078125f / nrm;
  float sf = (lo - tmin) / k - 1.0f;
  float lf = (hi - tmin) / k + 1.0f;
  int first = (int)ceilf (fmaxf(0.f,  fminf(445.f, sf)));
  int last  = (int)floorf(fmaxf(-1.f, fminf(445.f, lf)));
  int n_s = (lf >= sf && last >= first) ? (last - first + 1) : 0;
  int base = 0;
  if (n_s > 0) base = atomicAdd(cnt, n_s);
  rayi[r] = make_int4(base, first, n_s, 0);
}

// ============ kernel 2 (fused aux): embW + slot fill + weight/bias pack =======
extern "C" __global__ void __launch_bounds__(256)
k_aux(const float* __restrict__ viewdirs, const int4* __restrict__ rayi,
      int* __restrict__ slot_map,
      const float* __restrict__ mW1, const float* __restrict__ mW2,
      const float* __restrict__ mW3, const float* __restrict__ fv,
      const float* __restrict__ pW1, const float* __restrict__ pW2,
      const float* __restrict__ pW3, const float* __restrict__ dW1,
      const float* __restrict__ dW2, const float* __restrict__ dW3,
      const float* __restrict__ dW4,
      const float* __restrict__ mb1, const float* __restrict__ mb2,
      const float* __restrict__ mb3, const float* __restrict__ pb1,
      const float* __restrict__ pb2, const float* __restrict__ pb3,
      const float* __restrict__ db1, const float* __restrict__ db2,
      const float* __restrict__ db3, const float* __restrict__ db4,
      f16* __restrict__ wts, float* __restrict__ bias,
      float* __restrict__ embW) {
  const int b = blockIdx.x, t = threadIdx.x;
  if (b < 1024) {                       // ---- embW (dir-embed folded into dW1)
    int idx = b * 256 + t;
    int ray = idx >> 6, o = idx & 63;
    float v0 = viewdirs[ray*3+0], v1 = viewdirs[ray*3+1], v2 = viewdirs[ray*3+2];
    float acc = db1[o];
    acc = fmaf(v0, dW1[15*64+o], acc);
    acc = fmaf(v1, dW1[16*64+o], acc);
    acc = fmaf(v2, dW1[17*64+o], acc);
#pragma unroll
    for (int fr = 0; fr < 6; ++fr) {
      float f = (float)(1 << fr);
      int rb = 18 + fr*6;
      acc = fmaf(sinf(v0*f), dW1[(rb+0)*64+o], acc);
      acc = fmaf(sinf(v1*f), dW1[(rb+1)*64+o], acc);
      acc = fmaf(sinf(v2*f), dW1[(rb+2)*64+o], acc);
      acc = fmaf(cosf(v0*f), dW1[(rb+3)*64+o], acc);
      acc = fmaf(cosf(v1*f), dW1[(rb+4)*64+o], acc);
      acc = fmaf(cosf(v2*f), dW1[(rb+5)*64+o], acc);
    }
    embW[idx] = acc;
  } else if (b < 1280) {                // ---- slot_map fill (16 rays/block)
    int ray = (b - 1024) * 16 + (t >> 4);
    int4 ri = rayi[ray];
    for (int i = t & 15; i < ri.z; i += 16)
      slot_map[ri.x + i] = (ray << 9) | (ri.y + i);
  } else if (b < 1460) {                // ---- weight pack (Wt[dout][KP], f16)
    int i = (b - 1280) * 256 + t;
    if (i >= W_TOT) return;
    float v = 0.f; int l, o, k;
    if (i < W_MW2)      { l=i;        o=l>>4; k=l&15;  if (k<4)  v = mW1[k*128+o]; }
    else if (i < W_MW3) { l=i-W_MW2;  o=l>>7; k=l&127; v = mW2[k*128+o]; }
    else if (i < W_FV)  { l=i-W_MW3;  o=l>>7; k=l&127; v = mW3[k*32+o]; }
    else if (i < W_P1)  { l=i-W_FV;   o=l>>5; k=l&31;  v = fv[k*64+o]; }
    else if (i < W_P2)  { l=i-W_P1;   o=l>>6; k=l&63;  v = pW1[k*64+o]; }
    else if (i < W_P3)  { l=i-W_P2;   o=l>>6; k=l&63;  v = pW2[k*64+o]; }
    else if (i < W_D1)  { l=i-W_P3;   o=l>>6; k=l&63;  if (o<16) v = pW3[k*16+o]; }
    else if (i < W_D2)  { l=i-W_D1;   o=l>>4; k=l&15;  if (k>=1) v = dW1[(k-1)*64+o]; }
    else if (i < W_D3)  { l=i-W_D2;   o=l>>6; k=l&63;  v = dW2[k*64+o]; }
    else if (i < W_D4)  { l=i-W_D3;   o=l>>6; k=l&63;  v = dW3[k*64+o]; }
    else                { l=i-W_D4;   o=l>>6; k=l&63;  if (o<3)  v = dW4[k*3+o]; }
    wts[i] = (f16)v;
  } else {                              // ---- bias slab (11 x 128 f32, padded)
    int i = (b - 1460) * 256 + t;
    if (i >= 1408) return;
    int L = i >> 7, o = i & 127;
    float v = 0.f;
    if      (L == 0)            v = mb1[o];
    else if (L == 1)            v = mb2[o];
    else if (L == 2 && o < 32)  v = mb3[o];
    else if (L == 4 && o < 64)  v = pb1[o];
    else if (L == 5 && o < 64)  v = pb2[o];
    else if (L == 6 && o < 16)  v = pb3[o];
    else if (L == 8 && o < 64)  v = db2[o];
    else if (L == 9 && o < 64)  v = db3[o];
    else if (L == 10 && o < 3)  v = db4[o];
    bias[i] = v;
  }
}

// ---- MFMA helpers (32x32x16, D[dout][sample] = W · X^T) ----
// A/B lane map (self-consistent): row/col = lane&31, k = (lane>>5)*8 + ks*16 + j
// C layout (m74/m101): col = lane&31 (sample), row = (reg&3) + 8*(reg>>2) + 4*(lane>>5)
template<int KS>
static __device__ __forceinline__ void load_b(const f16* Xb, int st, int lane,
                                              f16x8* B) {
  const int r = st*32 + (lane & 31);
  const int base = r*256 + ((lane >> 5) * 16);
#pragma unroll
  for (int ks = 0; ks < KS; ++ks) {
    int off = (base + ks*32) ^ ((r & 15) << 4);
    B[ks] = *(const f16x8*)((const char*)Xb + off);
  }
}

template<int KS>
static __device__ __forceinline__ void load_a(const f16* __restrict__ wbase,
                                              int dt, int lane, f16x8* A) {
  const f16* wp = wbase + (size_t)(dt*32 + (lane & 31)) * (KS*16) + (lane >> 5) * 8;
#pragma unroll
  for (int ks = 0; ks < KS; ++ks) A[ks] = *(const f16x8*)(wp + ks*16);
}

template<int KS>
static __device__ __forceinline__ f32x16 mm(const f16x8* A, const f16x8* B) {
  f32x16 acc;
#pragma unroll
  for (int i = 0; i < 16; ++i) acc[i] = 0.f;
#pragma unroll
  for (int ks = 0; ks < KS; ++ks)
    acc = __builtin_amdgcn_mfma_f32_32x32x16_f16(A[ks], B[ks], acc, 0, 0, 0);
  return acc;
}

template<bool RELU, int NQ>
static __device__ __forceinline__ void store_c(f16* Yb, int st, int dtb, int lane,
                                               const f32x16& acc,
                                               const float* __restrict__ bp) {
  const int r = st*32 + (lane & 31);
  const int gp = (lane >> 5) * 4;
#pragma unroll
  for (int q = 0; q < NQ; ++q) {
    const int db = dtb + q*8 + gp;
    f32x4 b4 = *(const f32x4*)(bp + db);
    float v0 = acc[4*q+0]+b4[0], v1 = acc[4*q+1]+b4[1];
    float v2 = acc[4*q+2]+b4[2], v3 = acc[4*q+3]+b4[3];
    if (RELU) {
      v0 = fmaxf(v0,0.f); v1 = fmaxf(v1,0.f);
      v2 = fmaxf(v2,0.f); v3 = fmaxf(v3,0.f);
    }
    f16x4 o = {(f16)v0,(f16)v1,(f16)v2,(f16)v3};
    int off = (r*256 + db*2) ^ ((r & 15) << 4);
    *(f16x4*)((char*)Yb + off) = o;
  }
}

// ---- interp prefetch: one (sample, channel) per thread ----
struct Pf {
  float v[8];
  float fx, fy, fz;
  int pk;
};

static __device__ __forceinline__ void pf_issue(
    int slot, int total, int c,
    const int* __restrict__ slot_map, const float2* __restrict__ rayf,
    const float* __restrict__ rays_o, const float* __restrict__ rays_d,
    const float* __restrict__ grid, Pf& P) {
  if (slot >= total) {
    P.pk = -2; P.fx = P.fy = P.fz = 0.f;
#pragma unroll
    for (int i = 0; i < 8; ++i) P.v[i] = 0.f;
    return;
  }
  int mi = slot_map[slot];
  int ray = mi >> 9, s = mi & 511;
  float2 tf = rayf[ray];
  float ox = rays_o[ray*3+0], oy = rays_o[ray*3+1], oz = rays_o[ray*3+2];
  float dx = rays_d[ray*3+0], dy = rays_d[ray*3+1], dz = rays_d[ray*3+2];
  float px, py, pz;
  sample_point(ox,oy,oz,dx,dy,dz, tf.x, tf.y, s, px,py,pz);
  P.pk = ray*2 + in_box(px,py,pz);
  float ixf = fminf(fmaxf((px + 1.f) * 0.5f * 255.f, 0.f), 255.f);
  float iyf = fminf(fmaxf((py + 1.f) * 0.5f * 255.f, 0.f), 255.f);
  float izf = fminf(fmaxf((pz + 1.f) * 0.5f * 255.f, 0.f), 255.f);
  int x0 = min((int)ixf, 254), y0 = min((int)iyf, 254), z0 = min((int)izf, 254);
  P.fx = ixf - (float)x0; P.fy = iyf - (float)y0; P.fz = izf - (float)z0;
  const float* gc = grid + (size_t)c * 16777216u;
  int bx0 = x0 << 16, bx1 = bx0 + 65536;
  int by0 = y0 << 8,  by1 = by0 + 256;
  P.v[0] = gc[bx0+by0+z0]; P.v[1] = gc[bx0+by0+z0+1];
  P.v[2] = gc[bx0+by1+z0]; P.v[3] = gc[bx0+by1+z0+1];
  P.v[4] = gc[bx1+by0+z0]; P.v[5] = gc[bx1+by0+z0+1];
  P.v[6] = gc[bx1+by1+z0]; P.v[7] = gc[bx1+by1+z0+1];
}

// ============ kernel 3: persistent 32x32-MFMA MLP pipeline ============
extern "C" __global__ void __launch_bounds__(512)
k_mlp(const float* __restrict__ rays_o, const float* __restrict__ rays_d,
      const float* __restrict__ grid, const int* __restrict__ slot_map,
      const float2* __restrict__ rayf, const float* __restrict__ embW,
      const f16* __restrict__ wts, const float* __restrict__ bias,
      int* __restrict__ cnt, unsigned short* __restrict__ ws4h) {
  const int total = cnt[0];
  const int nch = (total + 127) >> 7;
  int* qh = cnt + 1;
  const int tid = threadIdx.x;
  const int wv = tid >> 6, lane = tid & 63;
  const int sl = tid >> 2, ch = tid & 3;    // interp: 1 (sample,channel)/thread
  const int dthi = wv >> 2;                 // 0/1 : dout-half for MT=2 layers
  const int stw = wv & 3;                   // sample-tile for MT>=2 layers

  __shared__ __align__(16) f16 X[SB*128];
  __shared__ __align__(16) f16 Y[SB*128];
  __shared__ int sinfo[SB];
  __shared__ int q_next;                    // block-uniform work queue slot

  // ---- register-resident weights (loaded once, live across all chunks) ----
  f16x8 aMW1a[1], aMW1b[1], aFV[2], aP1[4], aP2[4], aD1[1], aD2[4], aD3[4];
  load_a<1>(wts+W_MW1, dthi,   lane, aMW1a);
  load_a<1>(wts+W_MW1, dthi+2, lane, aMW1b);
  load_a<2>(wts+W_FV,  dthi,   lane, aFV);
  load_a<4>(wts+W_P1,  dthi,   lane, aP1);
  load_a<4>(wts+W_P2,  dthi,   lane, aP2);
  load_a<1>(wts+W_D1,  dthi,   lane, aD1);
  load_a<4>(wts+W_D2,  dthi,   lane, aD2);
  load_a<4>(wts+W_D3,  dthi,   lane, aD3);
  f16x8 aP3[4], aD4[4];
  if (wv < 4) {
    load_a<4>(wts+W_P3, 0, lane, aP3);
    load_a<4>(wts+W_D4, 0, lane, aD4);
  }

  // ---- block-uniform initial pop ----
  if (tid == 0) q_next = atomicAdd(qh, 1);
  __syncthreads();
  int cur = q_next;

  Pf P;
  pf_issue((cur < nch) ? cur*128 + sl : total, total, ch,
           slot_map, rayf, rays_o, rays_d, grid, P);

  while (cur < nch) {
    const int blockbase = cur << 7;
    if (tid == 0) q_next = atomicAdd(qh, 1);   // pop next (visible after bar)

    // ---- consume prefetch: trilinear -> X[., 0..3]; zero-pad dims 4..15 ----
    {
      float c00 = P.v[0]*(1.f-P.fz) + P.v[1]*P.fz;
      float c01 = P.v[2]*(1.f-P.fz) + P.v[3]*P.fz;
      float c10 = P.v[4]*(1.f-P.fz) + P.v[5]*P.fz;
      float c11 = P.v[6]*(1.f-P.fz) + P.v[7]*P.fz;
      float c0v = c00*(1.f-P.fy) + c01*P.fy;
      float c1v = c10*(1.f-P.fy) + c11*P.fy;
      float mv  = c0v*(1.f-P.fx) + c1v*P.fx;
      if (ch == 0) sinfo[sl] = P.pk;
      int off = (sl*256 + ch*2) ^ ((sl & 15) << 4);
      *(f16*)((char*)X + off) = (f16)mv;
      if (ch < 3) {        // zero bytes 8..31 (dims 4..15), 3x b64 per row
        int zo = (sl*256 + 8 + ch*8) ^ ((sl & 15) << 4);
        *(unsigned long long*)((char*)X + zo) = 0ull;
      }
    }
    bar_lds();             // X, sinfo, q_next all visible
    const int nxt = q_next;
    pf_issue((nxt < nch) ? nxt*128 + sl : total, total, ch,
             slot_map, rayf, rays_o, rays_d, grid, P);

    float alpha_reg = 0.f; int pk_reg = -2;

    // ---- MW1 (KP=16, NP=128): X -> Y, relu ----
    { f16x8 B[1]; load_b<1>(X, stw, lane, B);
      f32x16 a0 = mm<1>(aMW1a, B);
      store_c<true,4>(Y, stw, dthi*32, lane, a0, bias + 0*128);
      f32x16 a1 = mm<1>(aMW1b, B);
      store_c<true,4>(Y, stw, (dthi+2)*32, lane, a1, bias + 0*128);
    } bar_lds();

    // ---- MW2 (KP=128, NP=128): Y -> X, relu (A streamed from L1) ----
    { f16x8 B[8]; load_b<8>(Y, stw, lane, B);
      f16x8 A8[8];
      load_a<8>(wts+W_MW2, dthi, lane, A8);
      f32x16 a0 = mm<8>(A8, B);
      store_c<true,4>(X, stw, dthi*32, lane, a0, bias + 1*128);
      load_a<8>(wts+W_MW2, dthi+2, lane, A8);
      f32x16 a1 = mm<8>(A8, B);
      store_c<true,4>(X, stw, (dthi+2)*32, lane, a1, bias + 1*128);
    } bar_lds();

    // ---- MW3 (KP=128, NP=32) + fused softmax: X -> Y (waves 0-3) ----
    if (wv < 4) {
      f16x8 B[8]; load_b<8>(X, wv, lane, B);
      f16x8 A8[8]; load_a<8>(wts+W_MW3, 0, lane, A8);
      f32x16 acc = mm<8>(A8, B);
      const int gp = (lane >> 5) * 4;
      float v[16];
#pragma unroll
      for (int q = 0; q < 4; ++q) {
        f32x4 b4 = *(const f32x4*)(bias + 2*128 + q*8 + gp);
#pragma unroll
        for (int i = 0; i < 4; ++i) v[4*q+i] = acc[4*q+i] + b4[i];
      }
      float mx = v[0];
#pragma unroll
      for (int i = 1; i < 16; ++i) mx = fmaxf(mx, v[i]);
      mx = fmaxf(mx, __shfl_xor(mx, 32));
      float s = 0.f;
#pragma unroll
      for (int i = 0; i < 16; ++i) { v[i] = expf(v[i] - mx); s += v[i]; }
      s += __shfl_xor(s, 32);
      float inv = 1.f / s;
      const int r = wv*32 + (lane & 31);
#pragma unroll
      for (int q = 0; q < 4; ++q) {
        const int db = q*8 + gp;
        f16x4 o = {(f16)(v[4*q+0]*inv), (f16)(v[4*q+1]*inv),
                   (f16)(v[4*q+2]*inv), (f16)(v[4*q+3]*inv)};
        int off = (r*256 + db*2) ^ ((r & 15) << 4);
        *(f16x4*)((char*)Y + off) = o;
      }
    }
    bar_lds();

    // ---- FV (KP=32, NP=64): Y -> X, no act ----
    { f16x8 B[2]; load_b<2>(Y, stw, lane, B);
      f32x16 a0 = mm<2>(aFV, B);
      store_c<false,4>(X, stw, dthi*32, lane, a0, bias + 3*128);
    } bar_lds();

    // ---- P1: X -> Y relu ----
    { f16x8 B[4]; load_b<4>(X, stw, lane, B);
      f32x16 a0 = mm<4>(aP1, B);
      store_c<true,4>(Y, stw, dthi*32, lane, a0, bias + 4*128);
    } bar_lds();

    // ---- P2: Y -> X relu ----
    { f16x8 B[4]; load_b<4>(Y, stw, lane, B);
      f32x16 a0 = mm<4>(aP2, B);
      store_c<true,4>(X, stw, dthi*32, lane, a0, bias + 5*128);
    } bar_lds();

    // ---- P3 (KP=64, NP=16pad): X -> Y[0..15] (waves 0-3); alpha in reg ----
    if (wv < 4) {
      f16x8 B[4]; load_b<4>(X, wv, lane, B);
      f32x16 acc = mm<4>(aP3, B);
      pk_reg = sinfo[wv*32 + (lane & 31)];
      if (lane < 32) {
        alpha_reg = 0.f;
        if (pk_reg >= 0 && (pk_reg & 1)) {
          float x = acc[0] + bias[6*128 + 0] + ACT_SHIFT;
          float sp = fmaxf(x, 0.f) + log1pf(expf(-fabsf(x)));
          alpha_reg = 1.f - expf(-sp);
        }
      }
      store_c<false,2>(Y, wv, 0, lane, acc, bias + 6*128);
    }
    bar_lds();

    // ---- D1 (KP=16, NP=64): Y -> X relu, per-ray embW bias ----
    { f16x8 B[1]; load_b<1>(Y, stw, lane, B);
      f32x16 acc = mm<1>(aD1, B);
      int pkc = sinfo[stw*32 + (lane & 31)];
      int ry = (pkc < 0) ? 0 : (pkc >> 1);
      store_c<true,4>(X, stw, dthi*32, lane, acc, embW + (size_t)ry*64);
    } bar_lds();

    // ---- D2: X -> Y relu ----
    { f16x8 B[4]; load_b<4>(X, stw, lane, B);
      f32x16 a0 = mm<4>(aD2, B);
      store_c<true,4>(Y, stw, dthi*32, lane, a0, bias + 8*128);
    } bar_lds();

    // ---- D3: Y -> X relu ----
    { f16x8 B[4]; load_b<4>(Y, stw, lane, B);
      f32x16 a0 = mm<4>(aD3, B);
      store_c<true,4>(X, stw, dthi*32, lane, a0, bias + 9*128);
    } bar_lds();

    // ---- D4 (KP=64, NP=16pad): X -> ws4h (waves 0-3, lanes<32) ----
    if (wv < 4) {
      f16x8 B[4]; load_b<4>(X, wv, lane, B);
      f32x16 acc = mm<4>(aD4, B);
      if (lane < 32 && pk_reg >= 0) {
        const float* bp = bias + 10*128;
        bool val = (pk_reg & 1) != 0;
        ushort4 u;
        u.x = f2h(alpha_reg);
        u.y = f2h(val ? 1.f/(1.f+expf(-(acc[0]+bp[0]))) : 0.f);
        u.z = f2h(val ? 1.f/(1.f+expf(-(acc[1]+bp[1]))) : 0.f);
        u.w = f2h(val ? 1.f/(1.f+expf(-(acc[2]+bp[2]))) : 0.f);
        *(ushort4*)(ws4h + (size_t)(blockbase + wv*32 + (lane & 31))*4) = u;
      }
    }
    bar_lds();   // X/sinfo/q_next overwritten only after this point
    cur = nxt;
  }
}

// ============ kernel 4: per-ray transmittance scan over packed slots ==========
extern "C" __global__ void __launch_bounds__(256)
k_scan(const ushort4* __restrict__ ws4h, const int4* __restrict__ rayi,
       float* __restrict__ out) {
  const int wid = (blockIdx.x * 256 + threadIdx.x) >> 6;
  const int ln  = threadIdx.x & 63;
  if (wid >= 4096) return;
  int4 ri = rayi[wid];
  int base = ri.x, n_s = ri.z;

  float T = 1.0f, ar = 0.f, ag = 0.f, ab = 0.f;
  int nc = (n_s + 63) >> 6;
  for (int cck = 0; cck < nc; ++cck) {
    int j = cck*64 + ln;
    float a = 0.f, rr = 0.f, gg = 0.f, bb = 0.f;
    if (j < n_s) {
      ushort4 u = ws4h[(size_t)base + j];
      a = h2f(u.x); rr = h2f(u.y); gg = h2f(u.z); bb = h2f(u.w);
    }
    float p = fmaxf(1.0f - a, 1e-10f);
#pragma unroll
    for (int off = 1; off < 64; off <<= 1) {
      float o = __shfl_up(p, off);
      if (ln >= off) p *= o;
    }
    float pe = __shfl_up(p, 1);
    if (ln == 0) pe = 1.0f;
    float wgt = a * T * pe;
    ar = fmaf(wgt, rr, ar);
    ag = fmaf(wgt, gg, ag);
    ab = fmaf(wgt, bb, ab);
    T *= __shfl(p, 63);
  }
#pragma unroll
  for (int off = 32; off; off >>= 1) {
    ar += __shfl_down(ar, off);
    ag += __shfl_down(ag, off);
    ab += __shfl_down(ab, off);
  }
  if (ln == 0) {
    out[wid*3+0] = ar + T;
    out[wid*3+1] = ag + T;
    out[wid*3+2] = ab + T;
  }
}

extern "C" void kernel_launch(void* const* d_in, const int* in_sizes, int n_in,
                              void* d_out, int out_size, void* d_ws, size_t ws_size,
                              hipStream_t stream) {
  const float* rays_o   = (const float*)d_in[0];
  const float* rays_d   = (const float*)d_in[1];
  const float* viewdirs = (const float*)d_in[2];
  const float* grid     = (const float*)d_in[3];
  const float* fv       = (const float*)d_in[4];
  const float* mW1 = (const float*)d_in[5];  const float* mb1 = (const float*)d_in[6];
  const float* mW2 = (const float*)d_in[7];  const float* mb2 = (const float*)d_in[8];
  const float* mW3 = (const float*)d_in[9];  const float* mb3 = (const float*)d_in[10];
  const float* pW1 = (const float*)d_in[11]; const float* pb1 = (const float*)d_in[12];
  const float* pW2 = (const float*)d_in[13]; const float* pb2 = (const float*)d_in[14];
  const float* pW3 = (const float*)d_in[15]; const float* pb3 = (const float*)d_in[16];
  const float* dW1 = (const float*)d_in[17]; const float* db1 = (const float*)d_in[18];
  const float* dW2 = (const float*)d_in[19]; const float* db2 = (const float*)d_in[20];
  const float* dW3 = (const float*)d_in[21]; const float* db3 = (const float*)d_in[22];
  const float* dW4 = (const float*)d_in[23]; const float* db4 = (const float*)d_in[24];
  float* out = (float*)d_out;

  char* ws = (char*)d_ws;
  int*     cnt      = (int*)(ws + OFF_CNT);
  int4*    rayi     = (int4*)(ws + OFF_RAYI);
  float2*  rayf     = (float2*)(ws + OFF_RAYF);
  float*   embW     = (float*)(ws + OFF_EMBW);
  f16*     wts      = (f16*)(ws + OFF_WTS);
  float*   bias     = (float*)(ws + OFF_BIAS);
  int*     slot_map = (int*)(ws + OFF_SLOT);
  unsigned short* ws4h = (unsigned short*)(ws + OFF_WS4H);

  hipMemsetAsync(cnt, 0, 8, stream);
  k_setup<<<16, 256, 0, stream>>>(rays_o, rays_d, cnt, rayi, rayf);
  k_aux<<<1466, 256, 0, stream>>>(viewdirs, rayi, slot_map,
                                  mW1, mW2, mW3, fv, pW1, pW2, pW3,
                                  dW1, dW2, dW3, dW4,
                                  mb1, mb2, mb3, pb1, pb2, pb3,
                                  db1, db2, db3, db4, wts, bias, embW);
  k_mlp<<<256, 512, 0, stream>>>(rays_o, rays_d, grid, slot_map, rayf,
                                 embW, wts, bias, cnt, ws4h);
  k_scan<<<1024, 256, 0, stream>>>((const ushort4*)ws4h, rayi, out);
}